// Round 6
// baseline (354.318 us; speedup 1.0000x reference)
//
#include <hip/hip_runtime.h>

// FilterInitializerLinear: conv3x3(512->512, pad1) on (192,512,22,22) fp32,
// PrRoIPool 4x4 per (image,seq) roi, mean over 3 images, /(C*16).
// Image n feeds exactly one roi -> conv only on roi-box positions, globally
// compacted (flat-N). Conv uses the round-1-proven 128x128/4-wave/32KB-LDS
// structure (2.5 blocks/CU resident -> cross-block latency hiding).

#define NIMG 192
#define CCH 512
#define FH 22
#define FW 22
#define SPATIAL 484
#define PADH 24
#define PADW 24
#define NTMAX 49152   // worst-case total compacted positions (192 * 256)

typedef __bf16 bf16;
typedef __bf16 bf16x2 __attribute__((ext_vector_type(2)));
typedef __bf16 bf16x8 __attribute__((ext_vector_type(8)));
typedef float f32x4 __attribute__((ext_vector_type(4)));

#define GLOBAL_AS __attribute__((address_space(1)))
#define LDS_AS __attribute__((address_space(3)))

__device__ __forceinline__ void gload_lds16(const void* g, void* l) {
  __builtin_amdgcn_global_load_lds((GLOBAL_AS const void*)g, (LDS_AS void*)l, 16, 0, 0);
}

// boxes[n*8]: {y0, x0, xw, xwp, yh, countp, -, -}; poff = boxes + NIMG*8,
// poff[0..192] prefix sums of countp (poff[192] = NT total).
__global__ void prep_kernel(const float* __restrict__ bb, int* __restrict__ boxes) {
  int n = threadIdx.x;
  if (n < NIMG) {
    const float scale = 1.f / 16.f;
    float x1s = bb[n * 4 + 0] * scale;
    float y1s = bb[n * 4 + 1] * scale;
    float x2s = (bb[n * 4 + 0] + bb[n * 4 + 2]) * scale;
    float y2s = (bb[n * 4 + 1] + bb[n * 4 + 3]) * scale;
    float binx = (x2s - x1s) * 0.25f;
    float biny = (y2s - y1s) * 0.25f;
    float endx = (x1s + 3 * binx) + binx;   // fp-identical to pool's bin-3 end
    float endy = (y1s + 3 * biny) + biny;
    int x0 = max(0, (int)floorf(x1s));
    int xc1 = min(FW - 1, (int)floorf(endx) + 1);
    int y0 = max(0, (int)floorf(y1s));
    int yc1 = min(FH - 1, (int)floorf(endy) + 1);
    int xw = xc1 - x0 + 1;
    int yh = yc1 - y0 + 1;
    int xwp = (xw + 1) & ~1;
    int* b = boxes + n * 8;
    b[0] = y0; b[1] = x0; b[2] = xw; b[3] = xwp; b[4] = yh; b[5] = yh * xwp;
    b[6] = 0; b[7] = 0;
  }
  __syncthreads();
  if (threadIdx.x == 0) {
    int* poff = boxes + NIMG * 8;
    int acc = 0;
    for (int i = 0; i < NIMG; ++i) {
      poff[i] = acc;
      acc += boxes[i * 8 + 5];
    }
    poff[NIMG] = acc;
  }
}

// ---- pass 1: fused. Blocks [0, NIMG*FH): feat fp32 NCHW -> bf16 padded NHWC
// via LDS transpose (rows outside box+halo skipped). Blocks [NIMG*FH, +CCH):
// conv_w (co,ci,3,3) -> Wb[co][pos][ci] bf16.
__global__ __launch_bounds__(256) void cast_pad_kernel(const float* __restrict__ feat,
                                                       bf16* __restrict__ Fp,
                                                       const float* __restrict__ cw,
                                                       bf16* __restrict__ Wb,
                                                       const int* __restrict__ boxes) {
  static __shared__ __align__(16) char smem[CCH * FW * 2];   // 22528 B
  int t = threadIdx.x;
  if (blockIdx.x >= NIMG * FH) {
    int co = blockIdx.x - NIMG * FH;
    float* lw = (float*)smem;
    const float* src = cw + (long)co * CCH * 9;
    #pragma unroll
    for (int k = 0; k < 18; ++k) lw[t + 256 * k] = src[t + 256 * k];
    __syncthreads();
    bf16* dst = Wb + (long)co * 9 * CCH;
    #pragma unroll
    for (int k = 0; k < 18; ++k) {
      int f = t + 256 * k;
      int pos = f >> 9;
      int ci = f & 511;
      dst[f] = (bf16)lw[ci * 9 + pos];
    }
    return;
  }
  bf16* lt = (bf16*)smem;   // [ci][x]
  int n = blockIdx.x / FH;
  int y = blockIdx.x % FH;
  int y0 = boxes[n * 8 + 0];
  int y1 = y0 + boxes[n * 8 + 4] - 1;
  if (y < y0 - 1 || y > y1 + 1) return;
  const float* fb = feat + (long)n * CCH * SPATIAL + y * FW;
  #pragma unroll 4
  for (int k = 0; k < 44; ++k) {            // 512*22 = 11264 = 256*44
    int f = t + 256 * k;
    int ci = f / FW;
    int x = f - ci * FW;
    lt[f] = (bf16)fb[(long)ci * SPATIAL + x];
  }
  __syncthreads();
  uint* od = (uint*)(Fp + (long)(n * PADH + y + 1) * PADW * CCH);
  #pragma unroll 4
  for (int k = 0; k < 24; ++k) {            // 24px * 256 uint = 6144
    int w = t + 256 * k;
    int px = w >> 8;
    int cp = w & 255;
    int ci = cp * 2;
    uint v = 0;
    if (px >= 1 && px <= FW) {
      bf16x2 pr;
      pr[0] = lt[ci * FW + px - 1];
      pr[1] = lt[(ci + 1) * FW + px - 1];
      v = __builtin_bit_cast(uint, pr);
    }
    od[w] = v;
  }
  if (y == 0 || y == FH - 1) {
    int py = (y == 0) ? 0 : PADH - 1;
    uint* oz = (uint*)(Fp + (long)(n * PADH + py) * PADW * CCH);
    #pragma unroll 4
    for (int k = 0; k < 24; ++k) oz[t + 256 * k] = 0u;
  }
}

// ---- pass 2: implicit-GEMM conv on flat compacted positions.
// Round-1-proven structure: 128co x 128s tile, BK=64, 4 waves (2x2),
// single 32KB LDS buffer, 2 barriers/K-step, both-sides XOR swizzle.
// ~2.5 blocks/CU resident -> cross-block overlap hides barrier drains.
// Grid 1536 = 4 co-tiles x 384 s-tiles (worst case; early exit past NT).
// XCD-bijective swizzle: each XCD gets a contiguous s-range; the 4 co-tiles
// of one s-tile are adjacent (share B reads in L2).
__global__ __launch_bounds__(256, 2) void conv_kernel(
    const bf16* __restrict__ Fp, const bf16* __restrict__ Wb,
    const float* __restrict__ bias, bf16* __restrict__ O,
    const int* __restrict__ boxes) {
  __shared__ __align__(16) bf16 As[128 * 64];
  __shared__ __align__(16) bf16 Bs[128 * 64];
  const int* poff = boxes + NIMG * 8;
  int NT = poff[NIMG];
  int b0 = blockIdx.x;
  int bid = (b0 & 7) * 192 + (b0 >> 3);   // 1536 = 8*192
  int st = bid >> 2;
  int mt = bid & 3;
  int s0 = st << 7;
  int co0 = mt << 7;
  if (s0 >= NT) return;   // block-uniform early exit

  int tid = threadIdx.x;
  int wv = tid >> 6, l = tid & 63;
  int wm = wv >> 1, wn = wv & 1;          // 2 M-waves x 2 N-waves, 64x64 each
  int lrow = l >> 3;                      // 0..7 : row within a wave-load
  int cg8 = ((l & 7) ^ lrow) << 3;        // inverse-swizzled global chunk (elems)

  long aOff[4];
  long bRow[4];
  #pragma unroll
  for (int j = 0; j < 4; ++j) {
    int row = j * 32 + wv * 8 + lrow;
    aOff[j] = (long)(co0 + row) * 9 * CCH + cg8;
    int sg = s0 + row;
    if (sg > NT - 1) sg = NT - 1;         // dup position; store masked
    // binary search: n s.t. poff[n] <= sg < poff[n+1]
    int lo = 0, hi = NIMG - 1;
    while (lo < hi) {
      int mid = (lo + hi + 1) >> 1;
      if (poff[mid] <= sg) lo = mid; else hi = mid - 1;
    }
    int n = lo;
    int local = sg - poff[n];
    const int* bx = boxes + n * 8;
    int y0 = bx[0], x0 = bx[1], xwp = bx[3];
    int r = local / xwp;
    int c = local - r * xwp;
    bRow[j] = ((long)(n * PADH + y0 + r) * PADW + x0 + c) * CCH + cg8;
  }

  const f32x4 vz = {0.f, 0.f, 0.f, 0.f};
  f32x4 acc[4][4];
  #pragma unroll
  for (int a = 0; a < 4; ++a)
    #pragma unroll
    for (int b = 0; b < 4; ++b) acc[a][b] = vz;

  for (int pos = 0; pos < 9; ++pos) {
    int ky = pos / 3, kx = pos - 3 * (pos / 3);
    long ash = (long)pos * CCH;
    long bsh = (long)(ky * PADW + kx) * CCH;
    for (int ci0 = 0; ci0 < CCH; ci0 += 64) {
      #pragma unroll
      for (int j = 0; j < 4; ++j) {
        gload_lds16(Wb + aOff[j] + ash + ci0, (char*)As + (j * 32 + wv * 8) * 128);
        gload_lds16(Fp + bRow[j] + bsh + ci0, (char*)Bs + (j * 32 + wv * 8) * 128);
      }
      __syncthreads();
      bf16x8 af[2][4], bfv[2][4];
      #pragma unroll
      for (int kk = 0; kk < 2; ++kk) {
        #pragma unroll
        for (int i = 0; i < 4; ++i) {
          int rowa = wm * 64 + i * 16 + (l & 15);
          int offa = rowa * 128 + kk * 64 + ((l >> 4) * 16);
          offa ^= (rowa & 7) << 4;
          af[kk][i] = *(const bf16x8*)((const char*)As + offa);
          int rowb = wn * 64 + i * 16 + (l & 15);
          int offb = rowb * 128 + kk * 64 + ((l >> 4) * 16);
          offb ^= (rowb & 7) << 4;
          bfv[kk][i] = *(const bf16x8*)((const char*)Bs + offb);
        }
      }
      #pragma unroll
      for (int kk = 0; kk < 2; ++kk)
        #pragma unroll
        for (int mi = 0; mi < 4; ++mi)
          #pragma unroll
          for (int nj = 0; nj < 4; ++nj)
            acc[mi][nj] = __builtin_amdgcn_mfma_f32_16x16x32_bf16(
                af[kk][mi], bfv[kk][nj], acc[mi][nj], 0, 0, 0);
      __syncthreads();
    }
  }

  // epilogue: C/D layout col=lane&15 (s), row=(lane>>4)*4+reg (co).
  // O layout: [co][gp] flat, stride NTMAX. Halo cols hold valid conv values
  // (pool weight is 0 there) so no masking beyond s < NT.
  #pragma unroll
  for (int nj = 0; nj < 4; ++nj) {
    int s = s0 + wn * 64 + nj * 16 + (l & 15);
    bool ok = (s < NT);
    #pragma unroll
    for (int mi = 0; mi < 4; ++mi) {
      #pragma unroll
      for (int rr = 0; rr < 4; ++rr) {
        if (ok) {
          int co = co0 + wm * 64 + mi * 16 + (l >> 4) * 4 + rr;
          float v = acc[mi][nj][rr] + bias[co];
          O[(long)co * NTMAX + s] = (bf16)v;
        }
      }
    }
  }
}

// ---- pass 3: PrRoIPool over flat O + mean over images + /(C*16).
// grid = 64 seqs * 8 c-chunks (512 blocks, 1 wave each).
__global__ __launch_bounds__(64) void pool_kernel(const bf16* __restrict__ O,
                                                  const float* __restrict__ bb,
                                                  const int* __restrict__ boxes,
                                                  float* __restrict__ out) {
  __shared__ float wys[4][FH];
  __shared__ float wxs[4][24];
  const int* poff = boxes + NIMG * 8;
  int ns = blockIdx.x >> 3;
  int chunk = blockIdx.x & 7;
  int lane = threadIdx.x;
  int c = chunk * 64 + lane;
  f32x4 acc[4];
  #pragma unroll
  for (int p = 0; p < 4; ++p) acc[p] = (f32x4){0.f, 0.f, 0.f, 0.f};

  for (int ni = 0; ni < 3; ++ni) {
    int n = ni * 64 + ns;
    __syncthreads();
    if (lane < 8) {
      int t = lane;
      int axis = t >> 2;
      int p = t & 3;
      const float scale = 1.f / 16.f;
      float bxv = bb[n * 4 + 0], byv = bb[n * 4 + 1];
      float bwv = bb[n * 4 + 2], bhv = bb[n * 4 + 3];
      float s1 = (axis ? bxv : byv) * scale;
      float s2 = ((axis ? bxv : byv) + (axis ? bwv : bhv)) * scale;
      float blen = (s2 - s1) * 0.25f;
      float start = s1 + p * blen;
      float end = start + blen;
      float inv = 1.0f / blen;          // folds 1/area into the weights
      float* wrow = axis ? &wxs[p][0] : &wys[p][0];
      int size = axis ? FW : FH;
      int zn = axis ? 24 : FH;
      for (int i = 0; i < zn; ++i) wrow[i] = 0.f;
      int s0i = (int)floorf(start);
      for (int k = 0; k < 6; ++k) {
        int cell = s0i + k;
        float cf = (float)cell;
        float a1 = fmaxf(start, cf);
        float a2 = fmaxf(fminf(end, cf + 1.f), a1);
        float alpha = a1 - cf, lim = a2 - cf;
        float f0 = (lim - 0.5f * lim * lim) - (alpha - 0.5f * alpha * alpha);
        float f1 = 0.5f * lim * lim - 0.5f * alpha * alpha;
        if (cell >= 0 && cell < size) wrow[cell] += f0 * inv;
        if (cell + 1 >= 0 && cell + 1 < size) wrow[cell + 1] += f1 * inv;
      }
    }
    __syncthreads();
    const int* bxp = boxes + n * 8;
    int y0 = bxp[0], x0 = bxp[1], xwp = bxp[3], yh = bxp[4];
    const bf16* Op = O + (long)c * NTMAX + poff[n];
    int khalf = xwp >> 1;
    for (int rr = 0; rr < yh; ++rr) {
      int y = y0 + rr;
      float w0 = wys[0][y], w1 = wys[1][y], w2 = wys[2][y], w3 = wys[3][y];
      const uint* rp = (const uint*)(Op + rr * xwp);
      for (int k = 0; k < khalf; ++k) {
        uint u = rp[k];
        bf16x2 pr = __builtin_bit_cast(bf16x2, u);
        #pragma unroll
        for (int h = 0; h < 2; ++h) {
          int j = x0 + 2 * k + h;        // absolute x; halo col weight is 0
          float v = (float)pr[h];
          float x0w = wxs[0][j], x1w = wxs[1][j], x2w = wxs[2][j], x3w = wxs[3][j];
          float t0 = w0 * v, t1 = w1 * v, t2 = w2 * v, t3 = w3 * v;
          acc[0][0] += t0 * x0w; acc[0][1] += t0 * x1w; acc[0][2] += t0 * x2w; acc[0][3] += t0 * x3w;
          acc[1][0] += t1 * x0w; acc[1][1] += t1 * x1w; acc[1][2] += t1 * x2w; acc[1][3] += t1 * x3w;
          acc[2][0] += t2 * x0w; acc[2][1] += t2 * x1w; acc[2][2] += t2 * x2w; acc[2][3] += t2 * x3w;
          acc[3][0] += t3 * x0w; acc[3][1] += t3 * x1w; acc[3][2] += t3 * x2w; acc[3][3] += t3 * x3w;
        }
      }
    }
  }
  const float fin = 1.f / (3.f * 512.f * 16.f);
  float* outp = out + ((long)(ns * CCH + c)) * 16;
  #pragma unroll
  for (int p = 0; p < 4; ++p) {
    f32x4 v = acc[p] * fin;
    *(f32x4*)(outp + p * 4) = v;
  }
}

extern "C" void kernel_launch(void* const* d_in, const int* in_sizes, int n_in,
                              void* d_out, int out_size, void* d_ws, size_t ws_size,
                              hipStream_t stream) {
  const float* feat = (const float*)d_in[0];
  const float* bb = (const float*)d_in[1];
  const float* cw = (const float*)d_in[2];
  const float* cb = (const float*)d_in[3];
  float* out = (float*)d_out;

  const size_t FP_BYTES = (size_t)NIMG * PADH * PADW * CCH * 2;     // 113,246,208
  const size_t WB_BYTES = (size_t)CCH * 9 * CCH * 2;                //   4,718,592
  const size_t O_BYTES = (size_t)CCH * NTMAX * 2;                   //  50,331,648
  const size_t BOX_BYTES = (size_t)(NIMG * 8 + NIMG + 8) * 4;
  if (ws_size < FP_BYTES + WB_BYTES + O_BYTES + BOX_BYTES) return;

  char* ws = (char*)d_ws;
  bf16* Fp = (bf16*)ws;
  bf16* Wb = (bf16*)(ws + FP_BYTES);
  bf16* O = (bf16*)(ws + FP_BYTES + WB_BYTES);
  int* boxes = (int*)(ws + FP_BYTES + WB_BYTES + O_BYTES);

  hipLaunchKernelGGL(prep_kernel, dim3(1), dim3(256), 0, stream, bb, boxes);
  hipLaunchKernelGGL(cast_pad_kernel, dim3(NIMG * FH + CCH), dim3(256), 0, stream,
                     feat, Fp, cw, Wb, boxes);
  hipLaunchKernelGGL(conv_kernel, dim3(1536), dim3(256), 0, stream, Fp, Wb, cb, O, boxes);
  hipLaunchKernelGGL(pool_kernel, dim3(64 * 8), dim3(64), 0, stream, O, bb, boxes, out);
}

// Round 7
// 250.693 us; speedup vs baseline: 1.4134x; 1.4134x over previous
//
#include <hip/hip_runtime.h>

// FilterInitializerLinear: conv3x3(512->512, pad1) on (192,512,22,22) fp32,
// PrRoIPool 4x4 per (image,seq) roi, mean over 3 images, /(C*16).
// Image n feeds exactly one roi -> conv only on roi-box positions, globally
// compacted (flat-N). Conv: 128x128/4-wave/32KB-LDS structure; XCD swizzle
// computed over the RUNTIME active-block range (round-5 lesson: static
// swizzle + early-exit concentrated all work on 4 of 8 XCDs).

#define NIMG 192
#define CCH 512
#define FH 22
#define FW 22
#define SPATIAL 484
#define PADH 24
#define PADW 24
#define NTMAX 49152   // worst-case total compacted positions (192 * 256)

typedef __bf16 bf16;
typedef __bf16 bf16x2 __attribute__((ext_vector_type(2)));
typedef __bf16 bf16x8 __attribute__((ext_vector_type(8)));
typedef float f32x4 __attribute__((ext_vector_type(4)));

#define GLOBAL_AS __attribute__((address_space(1)))
#define LDS_AS __attribute__((address_space(3)))

__device__ __forceinline__ void gload_lds16(const void* g, void* l) {
  __builtin_amdgcn_global_load_lds((GLOBAL_AS const void*)g, (LDS_AS void*)l, 16, 0, 0);
}

// boxes[n*8]: {y0, x0, xw, xwp, yh, countp, -, -}; poff = boxes + NIMG*8,
// poff[0..192] prefix sums of countp (poff[192] = NT total).
__global__ void prep_kernel(const float* __restrict__ bb, int* __restrict__ boxes) {
  int n = threadIdx.x;
  if (n < NIMG) {
    const float scale = 1.f / 16.f;
    float x1s = bb[n * 4 + 0] * scale;
    float y1s = bb[n * 4 + 1] * scale;
    float x2s = (bb[n * 4 + 0] + bb[n * 4 + 2]) * scale;
    float y2s = (bb[n * 4 + 1] + bb[n * 4 + 3]) * scale;
    float binx = (x2s - x1s) * 0.25f;
    float biny = (y2s - y1s) * 0.25f;
    float endx = (x1s + 3 * binx) + binx;   // fp-identical to pool's bin-3 end
    float endy = (y1s + 3 * biny) + biny;
    int x0 = max(0, (int)floorf(x1s));
    int xc1 = min(FW - 1, (int)floorf(endx) + 1);
    int y0 = max(0, (int)floorf(y1s));
    int yc1 = min(FH - 1, (int)floorf(endy) + 1);
    int xw = xc1 - x0 + 1;
    int yh = yc1 - y0 + 1;
    int xwp = (xw + 1) & ~1;
    int* b = boxes + n * 8;
    b[0] = y0; b[1] = x0; b[2] = xw; b[3] = xwp; b[4] = yh; b[5] = yh * xwp;
    b[6] = 0; b[7] = 0;
  }
  __syncthreads();
  if (threadIdx.x == 0) {
    int* poff = boxes + NIMG * 8;
    int acc = 0;
    for (int i = 0; i < NIMG; ++i) {
      poff[i] = acc;
      acc += boxes[i * 8 + 5];
    }
    poff[NIMG] = acc;
  }
}

// ---- pass 1: fused. Blocks [0, NIMG*FH): feat fp32 NCHW -> bf16 padded NHWC
// via LDS transpose (rows outside box+halo skipped). Blocks [NIMG*FH, +CCH):
// conv_w (co,ci,3,3) -> Wb[co][pos][ci] bf16.
__global__ __launch_bounds__(256) void cast_pad_kernel(const float* __restrict__ feat,
                                                       bf16* __restrict__ Fp,
                                                       const float* __restrict__ cw,
                                                       bf16* __restrict__ Wb,
                                                       const int* __restrict__ boxes) {
  static __shared__ __align__(16) char smem[CCH * FW * 2];   // 22528 B
  int t = threadIdx.x;
  if (blockIdx.x >= NIMG * FH) {
    int co = blockIdx.x - NIMG * FH;
    float* lw = (float*)smem;
    const float* src = cw + (long)co * CCH * 9;
    #pragma unroll
    for (int k = 0; k < 18; ++k) lw[t + 256 * k] = src[t + 256 * k];
    __syncthreads();
    bf16* dst = Wb + (long)co * 9 * CCH;
    #pragma unroll
    for (int k = 0; k < 18; ++k) {
      int f = t + 256 * k;
      int pos = f >> 9;
      int ci = f & 511;
      dst[f] = (bf16)lw[ci * 9 + pos];
    }
    return;
  }
  bf16* lt = (bf16*)smem;   // [ci][x]
  int n = blockIdx.x / FH;
  int y = blockIdx.x % FH;
  int y0 = boxes[n * 8 + 0];
  int y1 = y0 + boxes[n * 8 + 4] - 1;
  if (y < y0 - 1 || y > y1 + 1) return;
  const float* fb = feat + (long)n * CCH * SPATIAL + y * FW;
  #pragma unroll 4
  for (int k = 0; k < 44; ++k) {            // 512*22 = 11264 = 256*44
    int f = t + 256 * k;
    int ci = f / FW;
    int x = f - ci * FW;
    lt[f] = (bf16)fb[(long)ci * SPATIAL + x];
  }
  __syncthreads();
  uint* od = (uint*)(Fp + (long)(n * PADH + y + 1) * PADW * CCH);
  #pragma unroll 4
  for (int k = 0; k < 24; ++k) {            // 24px * 256 uint = 6144
    int w = t + 256 * k;
    int px = w >> 8;
    int cp = w & 255;
    int ci = cp * 2;
    uint v = 0;
    if (px >= 1 && px <= FW) {
      bf16x2 pr;
      pr[0] = lt[ci * FW + px - 1];
      pr[1] = lt[(ci + 1) * FW + px - 1];
      v = __builtin_bit_cast(uint, pr);
    }
    od[w] = v;
  }
  if (y == 0 || y == FH - 1) {
    int py = (y == 0) ? 0 : PADH - 1;
    uint* oz = (uint*)(Fp + (long)(n * PADH + py) * PADW * CCH);
    #pragma unroll 4
    for (int k = 0; k < 24; ++k) oz[t + 256 * k] = 0u;
  }
}

// ---- pass 2: implicit-GEMM conv on flat compacted positions.
// 128co x 128s tile, BK=64, 4 waves (2x2), single 32KB LDS buffer,
// 2 barriers/K-step, both-sides XOR swizzle. Grid 1536 (worst case);
// runtime-bijective XCD swizzle over the ACTIVE range [0, A) only.
__global__ __launch_bounds__(256, 2) void conv_kernel(
    const bf16* __restrict__ Fp, const bf16* __restrict__ Wb,
    const float* __restrict__ bias, bf16* __restrict__ O,
    const int* __restrict__ boxes) {
  __shared__ __align__(16) bf16 As[128 * 64];
  __shared__ __align__(16) bf16 Bs[128 * 64];
  const int* poff = boxes + NIMG * 8;
  int NT = poff[NIMG];
  int A = ((NT + 127) >> 7) << 2;          // active blocks = 4 co-tiles * n s-tiles
  int b0 = blockIdx.x;
  if (b0 >= A) return;                     // evenly spread over XCDs (b0%8)
  // bijective chunked XCD swizzle over [0, A): XCD k gets a contiguous wgid chunk
  int q = A >> 3, r = A & 7;
  int xcd = b0 & 7;
  int idx = b0 >> 3;
  int wgid = (xcd < r ? xcd * (q + 1) : r * (q + 1) + (xcd - r) * q) + idx;
  int st = wgid >> 2;                      // s-tile major, co fast (B shared in L2)
  int mt = wgid & 3;
  int s0 = st << 7;
  int co0 = mt << 7;

  int tid = threadIdx.x;
  int wv = tid >> 6, l = tid & 63;
  int wm = wv >> 1, wn = wv & 1;          // 2 M-waves x 2 N-waves, 64x64 each
  int lrow = l >> 3;                      // 0..7 : row within a wave-load
  int cg8 = ((l & 7) ^ lrow) << 3;        // inverse-swizzled global chunk (elems)

  long aOff[4];
  long bRow[4];
  #pragma unroll
  for (int j = 0; j < 4; ++j) {
    int row = j * 32 + wv * 8 + lrow;
    aOff[j] = (long)(co0 + row) * 9 * CCH + cg8;
    int sg = s0 + row;
    if (sg > NT - 1) sg = NT - 1;         // dup position; store masked
    // binary search: n s.t. poff[n] <= sg < poff[n+1]
    int lo = 0, hi = NIMG - 1;
    while (lo < hi) {
      int mid = (lo + hi + 1) >> 1;
      if (poff[mid] <= sg) lo = mid; else hi = mid - 1;
    }
    int n = lo;
    int local = sg - poff[n];
    const int* bx = boxes + n * 8;
    int y0 = bx[0], x0 = bx[1], xwp = bx[3];
    int rr = local / xwp;
    int cc = local - rr * xwp;
    bRow[j] = ((long)(n * PADH + y0 + rr) * PADW + x0 + cc) * CCH + cg8;
  }

  const f32x4 vz = {0.f, 0.f, 0.f, 0.f};
  f32x4 acc[4][4];
  #pragma unroll
  for (int a = 0; a < 4; ++a)
    #pragma unroll
    for (int b = 0; b < 4; ++b) acc[a][b] = vz;

  for (int pos = 0; pos < 9; ++pos) {
    int ky = pos / 3, kx = pos - 3 * (pos / 3);
    long ash = (long)pos * CCH;
    long bsh = (long)(ky * PADW + kx) * CCH;
    for (int ci0 = 0; ci0 < CCH; ci0 += 64) {
      #pragma unroll
      for (int j = 0; j < 4; ++j) {
        gload_lds16(Wb + aOff[j] + ash + ci0, (char*)As + (j * 32 + wv * 8) * 128);
        gload_lds16(Fp + bRow[j] + bsh + ci0, (char*)Bs + (j * 32 + wv * 8) * 128);
      }
      __syncthreads();
      bf16x8 af[2][4], bfv[2][4];
      #pragma unroll
      for (int kk = 0; kk < 2; ++kk) {
        #pragma unroll
        for (int i = 0; i < 4; ++i) {
          int rowa = wm * 64 + i * 16 + (l & 15);
          int offa = rowa * 128 + kk * 64 + ((l >> 4) * 16);
          offa ^= (rowa & 7) << 4;
          af[kk][i] = *(const bf16x8*)((const char*)As + offa);
          int rowb = wn * 64 + i * 16 + (l & 15);
          int offb = rowb * 128 + kk * 64 + ((l >> 4) * 16);
          offb ^= (rowb & 7) << 4;
          bfv[kk][i] = *(const bf16x8*)((const char*)Bs + offb);
        }
      }
      #pragma unroll
      for (int kk = 0; kk < 2; ++kk)
        #pragma unroll
        for (int mi = 0; mi < 4; ++mi)
          #pragma unroll
          for (int nj = 0; nj < 4; ++nj)
            acc[mi][nj] = __builtin_amdgcn_mfma_f32_16x16x32_bf16(
                af[kk][mi], bfv[kk][nj], acc[mi][nj], 0, 0, 0);
      __syncthreads();
    }
  }

  // epilogue: C/D layout col=lane&15 (s), row=(lane>>4)*4+reg (co).
  // O layout: [co][gp] flat, stride NTMAX. Halo cols hold valid conv values
  // (pool weight is 0 there) so no masking beyond s < NT.
  #pragma unroll
  for (int nj = 0; nj < 4; ++nj) {
    int s = s0 + wn * 64 + nj * 16 + (l & 15);
    bool ok = (s < NT);
    #pragma unroll
    for (int mi = 0; mi < 4; ++mi) {
      #pragma unroll
      for (int rr = 0; rr < 4; ++rr) {
        if (ok) {
          int co = co0 + wm * 64 + mi * 16 + (l >> 4) * 4 + rr;
          float v = acc[mi][nj][rr] + bias[co];
          O[(long)co * NTMAX + s] = (bf16)v;
        }
      }
    }
  }
}

// ---- pass 3: PrRoIPool over flat O + mean over images + /(C*16).
// grid = 64 seqs * 8 c-chunks (512 blocks, 1 wave each).
__global__ __launch_bounds__(64) void pool_kernel(const bf16* __restrict__ O,
                                                  const float* __restrict__ bb,
                                                  const int* __restrict__ boxes,
                                                  float* __restrict__ out) {
  __shared__ float wys[4][FH];
  __shared__ float wxs[4][24];
  const int* poff = boxes + NIMG * 8;
  int ns = blockIdx.x >> 3;
  int chunk = blockIdx.x & 7;
  int lane = threadIdx.x;
  int c = chunk * 64 + lane;
  f32x4 acc[4];
  #pragma unroll
  for (int p = 0; p < 4; ++p) acc[p] = (f32x4){0.f, 0.f, 0.f, 0.f};

  for (int ni = 0; ni < 3; ++ni) {
    int n = ni * 64 + ns;
    __syncthreads();
    if (lane < 8) {
      int t = lane;
      int axis = t >> 2;
      int p = t & 3;
      const float scale = 1.f / 16.f;
      float bxv = bb[n * 4 + 0], byv = bb[n * 4 + 1];
      float bwv = bb[n * 4 + 2], bhv = bb[n * 4 + 3];
      float s1 = (axis ? bxv : byv) * scale;
      float s2 = ((axis ? bxv : byv) + (axis ? bwv : bhv)) * scale;
      float blen = (s2 - s1) * 0.25f;
      float start = s1 + p * blen;
      float end = start + blen;
      float inv = 1.0f / blen;          // folds 1/area into the weights
      float* wrow = axis ? &wxs[p][0] : &wys[p][0];
      int size = axis ? FW : FH;
      int zn = axis ? 24 : FH;
      for (int i = 0; i < zn; ++i) wrow[i] = 0.f;
      int s0i = (int)floorf(start);
      for (int k = 0; k < 6; ++k) {
        int cell = s0i + k;
        float cf = (float)cell;
        float a1 = fmaxf(start, cf);
        float a2 = fmaxf(fminf(end, cf + 1.f), a1);
        float alpha = a1 - cf, lim = a2 - cf;
        float f0 = (lim - 0.5f * lim * lim) - (alpha - 0.5f * alpha * alpha);
        float f1 = 0.5f * lim * lim - 0.5f * alpha * alpha;
        if (cell >= 0 && cell < size) wrow[cell] += f0 * inv;
        if (cell + 1 >= 0 && cell + 1 < size) wrow[cell + 1] += f1 * inv;
      }
    }
    __syncthreads();
    const int* bxp = boxes + n * 8;
    int y0 = bxp[0], x0 = bxp[1], xwp = bxp[3], yh = bxp[4];
    const bf16* Op = O + (long)c * NTMAX + poff[n];
    int khalf = xwp >> 1;
    for (int rr = 0; rr < yh; ++rr) {
      int y = y0 + rr;
      float w0 = wys[0][y], w1 = wys[1][y], w2 = wys[2][y], w3 = wys[3][y];
      const uint* rp = (const uint*)(Op + rr * xwp);
      for (int k = 0; k < khalf; ++k) {
        uint u = rp[k];
        bf16x2 pr = __builtin_bit_cast(bf16x2, u);
        #pragma unroll
        for (int h = 0; h < 2; ++h) {
          int j = x0 + 2 * k + h;        // absolute x; halo col weight is 0
          float v = (float)pr[h];
          float x0w = wxs[0][j], x1w = wxs[1][j], x2w = wxs[2][j], x3w = wxs[3][j];
          float t0 = w0 * v, t1 = w1 * v, t2 = w2 * v, t3 = w3 * v;
          acc[0][0] += t0 * x0w; acc[0][1] += t0 * x1w; acc[0][2] += t0 * x2w; acc[0][3] += t0 * x3w;
          acc[1][0] += t1 * x0w; acc[1][1] += t1 * x1w; acc[1][2] += t1 * x2w; acc[1][3] += t1 * x3w;
          acc[2][0] += t2 * x0w; acc[2][1] += t2 * x1w; acc[2][2] += t2 * x2w; acc[2][3] += t2 * x3w;
          acc[3][0] += t3 * x0w; acc[3][1] += t3 * x1w; acc[3][2] += t3 * x2w; acc[3][3] += t3 * x3w;
        }
      }
    }
  }
  const float fin = 1.f / (3.f * 512.f * 16.f);
  float* outp = out + ((long)(ns * CCH + c)) * 16;
  #pragma unroll
  for (int p = 0; p < 4; ++p) {
    f32x4 v = acc[p] * fin;
    *(f32x4*)(outp + p * 4) = v;
  }
}

extern "C" void kernel_launch(void* const* d_in, const int* in_sizes, int n_in,
                              void* d_out, int out_size, void* d_ws, size_t ws_size,
                              hipStream_t stream) {
  const float* feat = (const float*)d_in[0];
  const float* bb = (const float*)d_in[1];
  const float* cw = (const float*)d_in[2];
  const float* cb = (const float*)d_in[3];
  float* out = (float*)d_out;

  const size_t FP_BYTES = (size_t)NIMG * PADH * PADW * CCH * 2;     // 113,246,208
  const size_t WB_BYTES = (size_t)CCH * 9 * CCH * 2;                //   4,718,592
  const size_t O_BYTES = (size_t)CCH * NTMAX * 2;                   //  50,331,648
  const size_t BOX_BYTES = (size_t)(NIMG * 8 + NIMG + 8) * 4;
  if (ws_size < FP_BYTES + WB_BYTES + O_BYTES + BOX_BYTES) return;

  char* ws = (char*)d_ws;
  bf16* Fp = (bf16*)ws;
  bf16* Wb = (bf16*)(ws + FP_BYTES);
  bf16* O = (bf16*)(ws + FP_BYTES + WB_BYTES);
  int* boxes = (int*)(ws + FP_BYTES + WB_BYTES + O_BYTES);

  hipLaunchKernelGGL(prep_kernel, dim3(1), dim3(256), 0, stream, bb, boxes);
  hipLaunchKernelGGL(cast_pad_kernel, dim3(NIMG * FH + CCH), dim3(256), 0, stream,
                     feat, Fp, cw, Wb, boxes);
  hipLaunchKernelGGL(conv_kernel, dim3(1536), dim3(256), 0, stream, Fp, Wb, cb, O, boxes);
  hipLaunchKernelGGL(pool_kernel, dim3(64 * 8), dim3(64), 0, stream, O, bb, boxes, out);
}

// Round 8
// 208.477 us; speedup vs baseline: 1.6996x; 1.2025x over previous
//
#include <hip/hip_runtime.h>

// FilterInitializerLinear: conv3x3(512->512, pad1) on (192,512,22,22) fp32,
// PrRoIPool 4x4 per (image,seq) roi, mean over 3 images, /(C*16).
// Image n feeds exactly one roi -> conv only on roi-box positions, globally
// compacted (flat-N). Conv: 128x128/4-wave/32KB-LDS at its ~927 TF structure
// ceiling. This round: aux kernels (prep scan, col-restricted cast, 3-wave pool).

#define NIMG 192
#define CCH 512
#define FH 22
#define FW 22
#define SPATIAL 484
#define PADH 24
#define PADW 24
#define NTMAX 49152   // worst-case total compacted positions (192 * 256)

typedef __bf16 bf16;
typedef __bf16 bf16x2 __attribute__((ext_vector_type(2)));
typedef __bf16 bf16x8 __attribute__((ext_vector_type(8)));
typedef float f32x4 __attribute__((ext_vector_type(4)));

#define GLOBAL_AS __attribute__((address_space(1)))
#define LDS_AS __attribute__((address_space(3)))

__device__ __forceinline__ void gload_lds16(const void* g, void* l) {
  __builtin_amdgcn_global_load_lds((GLOBAL_AS const void*)g, (LDS_AS void*)l, 16, 0, 0);
}

// boxes[n*8]: {y0, x0, xw, xwp, yh, countp, -, -}; poff = boxes + NIMG*8,
// poff[0..192] prefix of countp. wyt[n][22][4] / wxt[n][24][4]: pool weights
// (pre-divided by bin length -> fold 1/area), computed with bin arithmetic
// fp-identical to the box bounds so the box is a superset of nonzero weights.
__global__ __launch_bounds__(256) void prep_kernel(const float* __restrict__ bb,
                                                   int* __restrict__ boxes,
                                                   float* __restrict__ wyt,
                                                   float* __restrict__ wxt) {
  __shared__ int sc[256];
  int t = threadIdx.x;
  const float scale = 1.f / 16.f;
  int cnt = 0;
  if (t < NIMG) {
    int n = t;
    float x1s = bb[n * 4 + 0] * scale;
    float y1s = bb[n * 4 + 1] * scale;
    float x2s = (bb[n * 4 + 0] + bb[n * 4 + 2]) * scale;
    float y2s = (bb[n * 4 + 1] + bb[n * 4 + 3]) * scale;
    float binx = (x2s - x1s) * 0.25f;
    float biny = (y2s - y1s) * 0.25f;
    float endx = (x1s + 3 * binx) + binx;   // == weight-table bin-3 end
    float endy = (y1s + 3 * biny) + biny;
    int x0 = max(0, (int)floorf(x1s));
    int xc1 = min(FW - 1, (int)floorf(endx) + 1);
    int y0 = max(0, (int)floorf(y1s));
    int yc1 = min(FH - 1, (int)floorf(endy) + 1);
    int xw = xc1 - x0 + 1;
    int yh = yc1 - y0 + 1;
    int xwp = (xw + 1) & ~1;
    int* b = boxes + n * 8;
    b[0] = y0; b[1] = x0; b[2] = xw; b[3] = xwp; b[4] = yh; b[5] = yh * xwp;
    b[6] = 0; b[7] = 0;
    cnt = yh * xwp;
  }
  // zero weight tables (wyt and wxt are contiguous: 8832 f32x4 total)
  f32x4* wz = (f32x4*)wyt;
  for (int k = 0; k < 35; ++k) {
    int idx = t + 256 * k;
    if (idx < 8832) wz[idx] = (f32x4){0.f, 0.f, 0.f, 0.f};
  }
  __syncthreads();
  // weight fill: item = (n, axis, p); disjoint float lanes -> no races
  for (int k = 0; k < 6; ++k) {
    int item = t + 256 * k;   // < 1536
    int n = item >> 3;
    int axis = (item >> 2) & 1;
    int p = item & 3;
    float a0 = axis ? bb[n * 4 + 0] : bb[n * 4 + 1];
    float aw = axis ? bb[n * 4 + 2] : bb[n * 4 + 3];
    float s1 = a0 * scale;
    float s2 = (a0 + aw) * scale;
    float blen = (s2 - s1) * 0.25f;
    float start = s1 + p * blen;
    float end = start + blen;
    float inv = 1.0f / blen;
    int size = axis ? FW : FH;
    float* base = axis ? (wxt + n * 24 * 4) : (wyt + n * 22 * 4);
    int s0i = (int)floorf(start);
    for (int kk = 0; kk < 6; ++kk) {
      int cell = s0i + kk;
      float cf = (float)cell;
      float a1 = fmaxf(start, cf);
      float a2 = fmaxf(fminf(end, cf + 1.f), a1);
      float alpha = a1 - cf, lim = a2 - cf;
      float f0 = (lim - 0.5f * lim * lim) - (alpha - 0.5f * alpha * alpha);
      float f1 = 0.5f * lim * lim - 0.5f * alpha * alpha;
      if (cell >= 0 && cell < size) base[cell * 4 + p] += f0 * inv;
      if (cell + 1 >= 0 && cell + 1 < size) base[(cell + 1) * 4 + p] += f1 * inv;
    }
  }
  // parallel prefix scan of countp (Hillis-Steele)
  sc[t] = cnt;
  __syncthreads();
  for (int ofs = 1; ofs < 256; ofs <<= 1) {
    int v = (t >= ofs) ? sc[t - ofs] : 0;
    __syncthreads();
    sc[t] += v;
    __syncthreads();
  }
  int* poff = boxes + NIMG * 8;
  if (t < NIMG) poff[t] = sc[t] - cnt;
  if (t == 255) poff[NIMG] = sc[255];
}

// ---- pass 1: fused. Blocks [0, NIMG*FH): feat fp32 NCHW -> bf16 padded NHWC
// via LDS transpose, restricted to box+halo rows AND columns. Blocks
// [NIMG*FH, +CCH): conv_w (co,ci,3,3) -> Wb[co][pos][ci] bf16.
__global__ __launch_bounds__(256) void cast_pad_kernel(const float* __restrict__ feat,
                                                       bf16* __restrict__ Fp,
                                                       const float* __restrict__ cw,
                                                       bf16* __restrict__ Wb,
                                                       const int* __restrict__ boxes) {
  static __shared__ __align__(16) char smem[CCH * FW * 2];   // 22528 B
  int t = threadIdx.x;
  if (blockIdx.x >= NIMG * FH) {
    int co = blockIdx.x - NIMG * FH;
    float* lw = (float*)smem;
    const float* src = cw + (long)co * CCH * 9;
    #pragma unroll
    for (int k = 0; k < 18; ++k) lw[t + 256 * k] = src[t + 256 * k];
    __syncthreads();
    bf16* dst = Wb + (long)co * 9 * CCH;
    #pragma unroll
    for (int k = 0; k < 18; ++k) {
      int f = t + 256 * k;
      int pos = f >> 9;
      int ci = f & 511;
      dst[f] = (bf16)lw[ci * 9 + pos];
    }
    return;
  }
  bf16* lt = (bf16*)smem;   // [ci][x]
  int n = blockIdx.x / FH;
  int y = blockIdx.x % FH;
  int y0 = boxes[n * 8 + 0];
  int y1 = y0 + boxes[n * 8 + 4] - 1;
  if (y < y0 - 1 || y > y1 + 1) return;
  int x0 = boxes[n * 8 + 1];
  int x1 = x0 + boxes[n * 8 + 2] - 1;
  int xr0 = max(0, x0 - 1);
  int xr1 = min(FW - 1, x1 + 1);   // lt cols actually consumed
  int xe = min(PADW - 1, x1 + 2);  // last padded col conv will read
  const float* fb = feat + (long)n * CCH * SPATIAL + y * FW;
  #pragma unroll 4
  for (int k = 0; k < 44; ++k) {            // 512*22 = 11264 = 256*44
    int f = t + 256 * k;
    int ci = f / FW;
    int x = f - ci * FW;
    if (x >= xr0 && x <= xr1) lt[f] = (bf16)fb[(long)ci * SPATIAL + x];
  }
  __syncthreads();
  uint* od = (uint*)(Fp + (long)(n * PADH + y + 1) * PADW * CCH);
  int ci = t * 2;
  for (int px = x0; px <= xe; ++px) {
    int x = px - 1;
    uint v = 0;
    if (x >= 0 && x <= FW - 1) {
      bf16x2 pr;
      pr[0] = lt[ci * FW + x];
      pr[1] = lt[(ci + 1) * FW + x];
      v = __builtin_bit_cast(uint, pr);
    }
    od[px * 256 + t] = v;
  }
  if (y == 0 || y == FH - 1) {   // zero pad rows (read only when box touches edge)
    int py = (y == 0) ? 0 : PADH - 1;
    uint* oz = (uint*)(Fp + (long)(n * PADH + py) * PADW * CCH);
    for (int px = x0; px <= xe; ++px) oz[px * 256 + t] = 0u;
  }
}

// ---- pass 2: implicit-GEMM conv on flat compacted positions.
// 128co x 128s tile, BK=64, 4 waves (2x2), single 32KB LDS buffer,
// 2 barriers/K-step, both-sides XOR swizzle, runtime-bijective XCD swizzle
// over the active range. Pad-column B rows clamp to the last real column so
// all reads stay inside cast_pad's written region.
__global__ __launch_bounds__(256, 2) void conv_kernel(
    const bf16* __restrict__ Fp, const bf16* __restrict__ Wb,
    const float* __restrict__ bias, bf16* __restrict__ O,
    const int* __restrict__ boxes) {
  __shared__ __align__(16) bf16 As[128 * 64];
  __shared__ __align__(16) bf16 Bs[128 * 64];
  const int* poff = boxes + NIMG * 8;
  int NT = poff[NIMG];
  int A = ((NT + 127) >> 7) << 2;          // active blocks = 4 co-tiles * n s-tiles
  int b0 = blockIdx.x;
  if (b0 >= A) return;                     // inactive spread evenly over XCDs
  int q = A >> 3, r = A & 7;
  int xcd = b0 & 7;
  int idx = b0 >> 3;
  int wgid = (xcd < r ? xcd * (q + 1) : r * (q + 1) + (xcd - r) * q) + idx;
  int st = wgid >> 2;                      // s-tile major, co fast (B shared in L2)
  int mt = wgid & 3;
  int s0 = st << 7;
  int co0 = mt << 7;

  int tid = threadIdx.x;
  int wv = tid >> 6, l = tid & 63;
  int wm = wv >> 1, wn = wv & 1;          // 2 M-waves x 2 N-waves, 64x64 each
  int lrow = l >> 3;                      // 0..7 : row within a wave-load
  int cg8 = ((l & 7) ^ lrow) << 3;        // inverse-swizzled global chunk (elems)

  long aOff[4];
  long bRow[4];
  #pragma unroll
  for (int j = 0; j < 4; ++j) {
    int row = j * 32 + wv * 8 + lrow;
    aOff[j] = (long)(co0 + row) * 9 * CCH + cg8;
    int sg = s0 + row;
    if (sg > NT - 1) sg = NT - 1;         // dup position; store masked
    // binary search: n s.t. poff[n] <= sg < poff[n+1]
    int lo = 0, hi = NIMG - 1;
    while (lo < hi) {
      int mid = (lo + hi + 1) >> 1;
      if (poff[mid] <= sg) lo = mid; else hi = mid - 1;
    }
    int n = lo;
    int local = sg - poff[n];
    const int* bx = boxes + n * 8;
    int y0 = bx[0], x0 = bx[1], xw = bx[2], xwp = bx[3];
    int rr = local / xwp;
    int cc = local - rr * xwp;
    if (cc >= xw) cc = xw - 1;            // pad col dups last real col (safe reads)
    bRow[j] = ((long)(n * PADH + y0 + rr) * PADW + x0 + cc) * CCH + cg8;
  }

  const f32x4 vz = {0.f, 0.f, 0.f, 0.f};
  f32x4 acc[4][4];
  #pragma unroll
  for (int a = 0; a < 4; ++a)
    #pragma unroll
    for (int b = 0; b < 4; ++b) acc[a][b] = vz;

  for (int pos = 0; pos < 9; ++pos) {
    int ky = pos / 3, kx = pos - 3 * (pos / 3);
    long ash = (long)pos * CCH;
    long bsh = (long)(ky * PADW + kx) * CCH;
    for (int ci0 = 0; ci0 < CCH; ci0 += 64) {
      #pragma unroll
      for (int j = 0; j < 4; ++j) {
        gload_lds16(Wb + aOff[j] + ash + ci0, (char*)As + (j * 32 + wv * 8) * 128);
        gload_lds16(Fp + bRow[j] + bsh + ci0, (char*)Bs + (j * 32 + wv * 8) * 128);
      }
      __syncthreads();
      bf16x8 af[2][4], bfv[2][4];
      #pragma unroll
      for (int kk = 0; kk < 2; ++kk) {
        #pragma unroll
        for (int i = 0; i < 4; ++i) {
          int rowa = wm * 64 + i * 16 + (l & 15);
          int offa = rowa * 128 + kk * 64 + ((l >> 4) * 16);
          offa ^= (rowa & 7) << 4;
          af[kk][i] = *(const bf16x8*)((const char*)As + offa);
          int rowb = wn * 64 + i * 16 + (l & 15);
          int offb = rowb * 128 + kk * 64 + ((l >> 4) * 16);
          offb ^= (rowb & 7) << 4;
          bfv[kk][i] = *(const bf16x8*)((const char*)Bs + offb);
        }
      }
      #pragma unroll
      for (int kk = 0; kk < 2; ++kk)
        #pragma unroll
        for (int mi = 0; mi < 4; ++mi)
          #pragma unroll
          for (int nj = 0; nj < 4; ++nj)
            acc[mi][nj] = __builtin_amdgcn_mfma_f32_16x16x32_bf16(
                af[kk][mi], bfv[kk][nj], acc[mi][nj], 0, 0, 0);
      __syncthreads();
    }
  }

  // epilogue: C/D layout col=lane&15 (s), row=(lane>>4)*4+reg (co).
  // O layout: [co][gp] flat, stride NTMAX. Pad cols hold dup'd real values
  // (pool weight 0) so no masking beyond s < NT.
  #pragma unroll
  for (int nj = 0; nj < 4; ++nj) {
    int s = s0 + wn * 64 + nj * 16 + (l & 15);
    bool ok = (s < NT);
    #pragma unroll
    for (int mi = 0; mi < 4; ++mi) {
      #pragma unroll
      for (int rr = 0; rr < 4; ++rr) {
        if (ok) {
          int co = co0 + wm * 64 + mi * 16 + (l >> 4) * 4 + rr;
          float v = acc[mi][nj][rr] + bias[co];
          O[(long)co * NTMAX + s] = (bf16)v;
        }
      }
    }
  }
}

// ---- pass 3: PrRoIPool over flat O + mean over images + /(C*16).
// grid = 64 seqs * 8 c-chunks (512 blocks); 192 threads = 3 waves, one wave
// per image; f32x4 weight tables in LDS; cross-wave LDS reduce at the end.
__global__ __launch_bounds__(192) void pool_kernel(const bf16* __restrict__ O,
                                                   const int* __restrict__ boxes,
                                                   const float* __restrict__ wyt,
                                                   const float* __restrict__ wxt,
                                                   float* __restrict__ out) {
  __shared__ f32x4 wtab[3][46];        // per wave: [0..21] wy rows, [22..45] wx cols
  __shared__ float red[2][16][64];
  const int* poff = boxes + NIMG * 8;
  int ns = blockIdx.x >> 3;
  int chunk = blockIdx.x & 7;
  int tid = threadIdx.x;
  int wv = tid >> 6;                   // image slot 0..2
  int lane = tid & 63;
  int c = chunk * 64 + lane;
  int n = wv * 64 + ns;
  if (lane < 46) {
    const float* src = (lane < 22) ? (wyt + ((long)n * 22 + lane) * 4)
                                   : (wxt + ((long)n * 24 + lane - 22) * 4);
    wtab[wv][lane] = *(const f32x4*)src;
  }
  const int* bxp = boxes + n * 8;
  int y0 = bxp[0], x0 = bxp[1], xwp = bxp[3], yh = bxp[4];
  const bf16* Op = O + (long)c * NTMAX + poff[n];   // poff even -> 4B aligned
  f32x4 acc4[4];
  #pragma unroll
  for (int p = 0; p < 4; ++p) acc4[p] = (f32x4){0.f, 0.f, 0.f, 0.f};
  int khalf = xwp >> 1;
  for (int rr = 0; rr < yh; ++rr) {
    f32x4 wy = wtab[wv][y0 + rr];
    const uint* rp = (const uint*)(Op + rr * xwp);
    for (int k = 0; k < khalf; ++k) {
      uint u = rp[k];
      bf16x2 pr = __builtin_bit_cast(bf16x2, u);
      #pragma unroll
      for (int h = 0; h < 2; ++h) {
        int j = x0 + 2 * k + h;        // absolute x; pad col weight is 0
        float v = (float)pr[h];
        f32x4 wx = wtab[wv][22 + j];
        acc4[0] += (wy[0] * v) * wx;
        acc4[1] += (wy[1] * v) * wx;
        acc4[2] += (wy[2] * v) * wx;
        acc4[3] += (wy[3] * v) * wx;
      }
    }
  }
  if (wv > 0) {
    #pragma unroll
    for (int p = 0; p < 4; ++p)
      #pragma unroll
      for (int qq = 0; qq < 4; ++qq) red[wv - 1][p * 4 + qq][lane] = acc4[p][qq];
  }
  __syncthreads();
  if (wv == 0) {
    const float fin = 1.f / (3.f * 512.f * 16.f);   // mean over images, /(C*F*F)
    float* outp = out + ((long)(ns * CCH + c)) * 16;
    #pragma unroll
    for (int p = 0; p < 4; ++p) {
      f32x4 rv = acc4[p];
      #pragma unroll
      for (int qq = 0; qq < 4; ++qq)
        rv[qq] += red[0][p * 4 + qq][lane] + red[1][p * 4 + qq][lane];
      *(f32x4*)(outp + p * 4) = rv * fin;
    }
  }
}

extern "C" void kernel_launch(void* const* d_in, const int* in_sizes, int n_in,
                              void* d_out, int out_size, void* d_ws, size_t ws_size,
                              hipStream_t stream) {
  const float* feat = (const float*)d_in[0];
  const float* bb = (const float*)d_in[1];
  const float* cw = (const float*)d_in[2];
  const float* cb = (const float*)d_in[3];
  float* out = (float*)d_out;

  const size_t FP_BYTES = (size_t)NIMG * PADH * PADW * CCH * 2;     // 113,246,208
  const size_t WB_BYTES = (size_t)CCH * 9 * CCH * 2;                //   4,718,592
  const size_t O_BYTES = (size_t)CCH * NTMAX * 2;                   //  50,331,648
  const size_t BOX_BYTES = 2048 * 4;                                // boxes + poff
  const size_t WYT_BYTES = (size_t)NIMG * 22 * 4 * 4;               //      67,584
  const size_t WXT_BYTES = (size_t)NIMG * 24 * 4 * 4;               //      73,728
  if (ws_size < FP_BYTES + WB_BYTES + O_BYTES + BOX_BYTES + WYT_BYTES + WXT_BYTES)
    return;

  char* ws = (char*)d_ws;
  bf16* Fp = (bf16*)ws;
  bf16* Wb = (bf16*)(ws + FP_BYTES);
  bf16* O = (bf16*)(ws + FP_BYTES + WB_BYTES);
  int* boxes = (int*)(ws + FP_BYTES + WB_BYTES + O_BYTES);
  float* wyt = (float*)(ws + FP_BYTES + WB_BYTES + O_BYTES + BOX_BYTES);
  float* wxt = wyt + (size_t)NIMG * 22 * 4;

  hipLaunchKernelGGL(prep_kernel, dim3(1), dim3(256), 0, stream, bb, boxes, wyt, wxt);
  hipLaunchKernelGGL(cast_pad_kernel, dim3(NIMG * FH + CCH), dim3(256), 0, stream,
                     feat, Fp, cw, Wb, boxes);
  hipLaunchKernelGGL(conv_kernel, dim3(1536), dim3(256), 0, stream, Fp, Wb, cb, O, boxes);
  hipLaunchKernelGGL(pool_kernel, dim3(64 * 8), dim3(192), 0, stream, O, boxes, wyt, wxt, out);
}